// Round 1
// baseline (29871.704 us; speedup 1.0000x reference)
//
#include <hip/hip_runtime.h>
#include <hip/hip_bf16.h>
#include <cstddef>

// LSTM: B=64, S=512, D=1024, H=1024. One persistent kernel, 256 WGs x 512 thr.
// WG b owns h-columns [4b, 4b+4) -> 16 gate cols. W/U bf16 slices resident in LDS.
// waves 0-3: x_t@W (16 batches each); waves 4-7: h_{t-1}@U. MFMA f32_16x16x32_bf16.
// Grid barrier: hand-rolled two-level sense counter (co-residency guaranteed:
// 70KB LDS -> <=2 WG/CU -> 256 WGs always resident on 256 CUs).

typedef __attribute__((ext_vector_type(8))) short short8;
typedef __attribute__((ext_vector_type(4))) float f32x4;

static constexpr int Bc = 64, Sc = 512, Dc = 1024, Hc = 1024, G4c = 4096;
static constexpr int WSTR = 1032;  // padded bf16 row stride: (n*516)%32 = n*4 -> 2-way max (free)

__device__ __forceinline__ unsigned short f2bf(float f) {
    unsigned int u = __float_as_uint(f);
    u = u + 0x7FFFu + ((u >> 16) & 1u);   // RNE
    return (unsigned short)(u >> 16);
}
__device__ __forceinline__ float sigmoidf_(float x) { return 1.0f / (1.0f + __expf(-x)); }
__device__ __forceinline__ float tanhf_(float x) { return 1.0f - 2.0f / (__expf(2.0f * x) + 1.0f); }  // overflow-safe

__global__ void __launch_bounds__(256) prep_kernel(const float* __restrict__ x,
                                                   unsigned short* __restrict__ x16,
                                                   unsigned int* __restrict__ bar,
                                                   int n4) {
    if (blockIdx.x == 0) {
        for (int i = threadIdx.x; i < 1024; i += 256) bar[i] = 0u;  // barrier state (ws is poisoned 0xAA)
    }
    int i = blockIdx.x * 256 + threadIdx.x;
    const int stride = gridDim.x * 256;
    for (; i < n4; i += stride) {
        const float4 v = ((const float4*)x)[i];
        ushort4 o;
        o.x = f2bf(v.x); o.y = f2bf(v.y); o.z = f2bf(v.z); o.w = f2bf(v.w);
        ((ushort4*)x16)[i] = o;
    }
}

// two-level barrier: 16 groups of 16 WGs -> root of 16. gen at bar[0], root at bar[16],
// group counters at bar[32 + 32*g] (128B apart).
__device__ __forceinline__ void grid_barrier(unsigned int* bar, unsigned int my_gen) {
    __builtin_amdgcn_fence(__ATOMIC_RELEASE, "agent");
    __syncthreads();
    if (threadIdx.x == 0) {
        const unsigned int grp = blockIdx.x >> 4;
        unsigned int a = __hip_atomic_fetch_add(&bar[32 + 32 * grp], 1u, __ATOMIC_ACQ_REL, __HIP_MEMORY_SCOPE_AGENT);
        bool released = false;
        if (a == 15u) {
            unsigned int r = __hip_atomic_fetch_add(&bar[16], 1u, __ATOMIC_ACQ_REL, __HIP_MEMORY_SCOPE_AGENT);
            if (r == 15u) {
                __hip_atomic_store(&bar[16], 0u, __ATOMIC_RELAXED, __HIP_MEMORY_SCOPE_AGENT);
                for (int g = 0; g < 16; ++g)
                    __hip_atomic_store(&bar[32 + 32 * g], 0u, __ATOMIC_RELAXED, __HIP_MEMORY_SCOPE_AGENT);
                __hip_atomic_store(&bar[0], my_gen, __ATOMIC_RELEASE, __HIP_MEMORY_SCOPE_AGENT);
                released = true;
            }
        }
        if (!released) {
            while (__hip_atomic_load(&bar[0], __ATOMIC_RELAXED, __HIP_MEMORY_SCOPE_AGENT) < my_gen)
                __builtin_amdgcn_s_sleep(1);
        }
    }
    __syncthreads();
    __builtin_amdgcn_fence(__ATOMIC_ACQUIRE, "agent");
}

__global__ void __launch_bounds__(512) lstm_persistent(
    const float* __restrict__ x,            // fp32 [B][S][D] (fallback path)
    const unsigned short* __restrict__ x16, // bf16 [B][S][D] (precast path)
    const float* __restrict__ W,            // [D][4H]
    const float* __restrict__ U,            // [H][4H]
    const float* __restrict__ bias,         // [4H]
    float* __restrict__ out,                // [B][S][H] ++ hT[B][H] ++ cT[B][H]
    unsigned short* __restrict__ h0,
    unsigned short* __restrict__ h1,
    unsigned int* __restrict__ bar,
    int use_x16) {
    __shared__ unsigned short Wl[16 * WSTR];
    __shared__ unsigned short Ul[16 * WSTR];
    __shared__ float gbuf[4][16][17];
    __shared__ float bias_l[16];

    const int tid = threadIdx.x;
    const int wv = tid >> 6;      // 0..7
    const int lane = tid & 63;
    const int q = lane >> 4;      // 0..3
    const int l16 = lane & 15;
    const int j0 = blockIdx.x * 4;

    // --- prologue: stage this WG's W/U slices into LDS (bf16), layout [n][k] k-fast ---
    for (int idx = tid; idx < 16 * Dc; idx += 512) {
        const int n = idx & 15;
        const int k = idx >> 4;
        const int gc = (n >> 2) * Hc + j0 + (n & 3);  // cols 0-3:i, 4-7:f, 8-11:g, 12-15:o
        Wl[n * WSTR + k] = f2bf(W[(size_t)k * G4c + gc]);
        Ul[n * WSTR + k] = f2bf(U[(size_t)k * G4c + gc]);
    }
    if (tid < 16) bias_l[tid] = bias[(tid >> 2) * Hc + j0 + (tid & 3)];
    // zero h0 (ws is poisoned each call)
    {
        const int g = blockIdx.x * 512 + tid;
        if (g < Bc * Hc) h0[g] = 0;
    }
    grid_barrier(bar, 1u);

    unsigned short* hcur = h0;
    unsigned short* hnxt = h1;

    float c_reg = 0.0f;
    const int jj = lane & 3;
    const int rb = lane >> 2;                 // 0..15
    const int bb = 16 * (wv & 3) + l16;       // A-row batch for MFMA (both halves)
    const int be = 16 * (wv & 3) + rb;        // elementwise batch (waves 0-3)
    const int jg = j0 + jj;

    for (int t = 0; t < Sc; ++t) {
        f32x4 acc0 = {0.f, 0.f, 0.f, 0.f};
        f32x4 acc1 = {0.f, 0.f, 0.f, 0.f};

        if (wv < 4) {
            // gates += x_t @ W   (A: x rows = 16 batches; B: Wl slice)
            const unsigned short* bbase = Wl + l16 * WSTR + q * 8;
            if (use_x16) {
                const unsigned short* abase = x16 + ((size_t)(bb * Sc + t)) * Dc + q * 8;
#pragma unroll
                for (int kk = 0; kk < 32; kk += 2) {
                    short8 a0 = *(const short8*)(abase + kk * 32);
                    short8 w0 = *(const short8*)(bbase + kk * 32);
                    acc0 = __builtin_amdgcn_mfma_f32_16x16x32_bf16(a0, w0, acc0, 0, 0, 0);
                    short8 a1 = *(const short8*)(abase + kk * 32 + 32);
                    short8 w1 = *(const short8*)(bbase + kk * 32 + 32);
                    acc1 = __builtin_amdgcn_mfma_f32_16x16x32_bf16(a1, w1, acc1, 0, 0, 0);
                }
            } else {
                const float* abase = x + ((size_t)(bb * Sc + t)) * Dc + q * 8;
#pragma unroll 4
                for (int kk = 0; kk < 32; ++kk) {
                    float4 f0 = *(const float4*)(abase + kk * 32);
                    float4 f1 = *(const float4*)(abase + kk * 32 + 4);
                    short8 a;
                    a[0] = (short)f2bf(f0.x); a[1] = (short)f2bf(f0.y);
                    a[2] = (short)f2bf(f0.z); a[3] = (short)f2bf(f0.w);
                    a[4] = (short)f2bf(f1.x); a[5] = (short)f2bf(f1.y);
                    a[6] = (short)f2bf(f1.z); a[7] = (short)f2bf(f1.w);
                    short8 w0 = *(const short8*)(bbase + kk * 32);
                    acc0 = __builtin_amdgcn_mfma_f32_16x16x32_bf16(a, w0, acc0, 0, 0, 0);
                }
            }
        } else {
            // gates += h_{t-1} @ U
            const unsigned short* abase = hcur + (size_t)bb * Hc + q * 8;
            const unsigned short* bbase = Ul + l16 * WSTR + q * 8;
#pragma unroll
            for (int kk = 0; kk < 32; kk += 2) {
                short8 a0 = *(const short8*)(abase + kk * 32);
                short8 u0 = *(const short8*)(bbase + kk * 32);
                acc0 = __builtin_amdgcn_mfma_f32_16x16x32_bf16(a0, u0, acc0, 0, 0, 0);
                short8 a1 = *(const short8*)(abase + kk * 32 + 32);
                short8 u1 = *(const short8*)(bbase + kk * 32 + 32);
                acc1 = __builtin_amdgcn_mfma_f32_16x16x32_bf16(a1, u1, acc1, 0, 0, 0);
            }
            // publish partial tile: C/D layout col=lane&15, row=q*4+r  [verified m89/m91]
#pragma unroll
            for (int r = 0; r < 4; ++r)
                gbuf[wv - 4][q * 4 + r][l16] = acc0[r] + acc1[r];
        }
        __syncthreads();
        if (wv < 4) {
            // combine xW + hU + bias, write full gate tile back to LDS
#pragma unroll
            for (int r = 0; r < 4; ++r) {
                float v = acc0[r] + acc1[r] + gbuf[wv][q * 4 + r][l16] + bias_l[l16];
                gbuf[wv][q * 4 + r][l16] = v;
            }
        }
        __syncthreads();
        if (wv < 4) {
            // lane -> (batch rb, column jj); gates at cols {jj, 4+jj, 8+jj, 12+jj}
            const float iv = sigmoidf_(gbuf[wv][rb][jj]);
            const float fv = sigmoidf_(gbuf[wv][rb][4 + jj]);
            const float gv = tanhf_(gbuf[wv][rb][8 + jj]);
            const float ov = sigmoidf_(gbuf[wv][rb][12 + jj]);
            c_reg = fv * c_reg + iv * gv;
            const float h = ov * tanhf_(c_reg);
            hnxt[be * Hc + jg] = f2bf(h);
            out[((size_t)be * Sc + t) * Hc + jg] = h;
            if (t == Sc - 1) {
                out[(size_t)Bc * Sc * Hc + (size_t)be * Hc + jg] = h;
                out[(size_t)Bc * Sc * Hc + (size_t)Bc * Hc + (size_t)be * Hc + jg] = c_reg;
            }
        }
        grid_barrier(bar, (unsigned int)(t + 2));
        unsigned short* tmp = hcur; hcur = hnxt; hnxt = tmp;
    }
}

extern "C" void kernel_launch(void* const* d_in, const int* in_sizes, int n_in,
                              void* d_out, int out_size, void* d_ws, size_t ws_size,
                              hipStream_t stream) {
    const float* x = (const float*)d_in[0];
    const float* W = (const float*)d_in[1];
    const float* U = (const float*)d_in[2];
    const float* bias = (const float*)d_in[3];
    float* out = (float*)d_out;

    // ws layout: h0 | h1 | bar | x16(optional)
    char* wsb = (char*)d_ws;
    unsigned short* h0 = (unsigned short*)wsb;                       // 131072 B
    unsigned short* h1 = (unsigned short*)(wsb + 131072);            // 131072 B
    unsigned int* bar = (unsigned int*)(wsb + 262144);               // 4096 B
    unsigned short* x16 = (unsigned short*)(wsb + 266240);           // 67,108,864 B
    const size_t need_x16 = 266240ull + (size_t)Bc * Sc * Dc * 2ull;
    const int use_x16 = (ws_size >= need_x16) ? 1 : 0;

    const int n4 = use_x16 ? (Bc * Sc * Dc) / 4 : 0;
    hipLaunchKernelGGL(prep_kernel, dim3(2048), dim3(256), 0, stream, x, x16, bar, n4);
    hipLaunchKernelGGL(lstm_persistent, dim3(256), dim3(512), 0, stream,
                       x, x16, W, U, bias, out, h0, h1, bar, use_x16);
}

// Round 2
// 18212.471 us; speedup vs baseline: 1.6402x; 1.6402x over previous
//
#include <hip/hip_runtime.h>
#include <hip/hip_bf16.h>
#include <cstddef>

// LSTM B=64,S=512,D=H=1024. Round 2 structure:
//  prep: bar init + x->bf16 ; transpose W,U -> [4096][1024] bf16 (W16T/U16T)
//  gemm_xw: xW = x@W precomputed to ws (fp32 if ws allows, else bf16, else in-loop)
//  lstm_rec: 256 WGs x 256 thr. 4 batch-blocks of 16 batches (independent!),
//   64 WGs/block each owning 16 h-cols. U-slice in REGISTERS (32 x short8/lane).
//   h exchanged via 32KB LDS stage (fragment-order, conflict-free). Per-block
//   tree barrier (4 leaves x 16 + root of 4) -> no global convoy.

typedef __attribute__((ext_vector_type(8))) short short8;
typedef __attribute__((ext_vector_type(4))) float f32x4;

static constexpr int Bc = 64, Sc = 512, Dc = 1024, Hc = 1024, G4c = 4096;

__device__ __forceinline__ unsigned short f2bf(float f) {
    unsigned int u = __float_as_uint(f);
    u = u + 0x7FFFu + ((u >> 16) & 1u);   // RNE
    return (unsigned short)(u >> 16);
}
__device__ __forceinline__ short f2bfs(float f) { return (short)f2bf(f); }
__device__ __forceinline__ float bf2f(unsigned short u) { return __uint_as_float(((unsigned int)u) << 16); }
__device__ __forceinline__ float sigmoidf_(float x) { return 1.0f / (1.0f + __expf(-x)); }
__device__ __forceinline__ float tanhf_(float x) { return 1.0f - 2.0f / (__expf(2.0f * x) + 1.0f); }

// ---------------- prep: barrier init + x fp32 -> bf16 ----------------
__global__ void __launch_bounds__(256) prep_misc(const float* __restrict__ x,
                                                 unsigned short* __restrict__ x16,
                                                 unsigned int* __restrict__ bar,
                                                 int n4, int use_x16) {
    if (blockIdx.x == 0) {
        for (int i = threadIdx.x; i < 1024; i += 256) bar[i] = 0u;
    }
    if (!use_x16) return;
    int i = blockIdx.x * 256 + threadIdx.x;
    const int stride = gridDim.x * 256;
    for (; i < n4; i += stride) {
        const float4 v = ((const float4*)x)[i];
        ushort4 o;
        o.x = f2bf(v.x); o.y = f2bf(v.y); o.z = f2bf(v.z); o.w = f2bf(v.w);
        ((ushort4*)x16)[i] = o;
    }
}

// ---------------- transpose [1024][4096] fp32 -> [4096][1024] bf16 ----------------
__global__ void __launch_bounds__(256) transpose_bf16(const float* __restrict__ src,
                                                      unsigned short* __restrict__ dst) {
    __shared__ unsigned short T[64][72];
    const int kt = blockIdx.x >> 6;   // 0..15
    const int gt = blockIdx.x & 63;   // 0..63
    const int tr = threadIdx.x >> 6;  // 0..3
    const int tc = threadIdx.x & 63;  // 0..63
#pragma unroll
    for (int i = 0; i < 16; ++i) {
        const int r = i * 4 + tr;
        T[tc][r] = f2bf(src[(size_t)(kt * 64 + r) * G4c + gt * 64 + tc]);
    }
    __syncthreads();
#pragma unroll
    for (int i = 0; i < 16; ++i) {
        const int g = i * 4 + tr;
        dst[(size_t)(gt * 64 + g) * 1024 + kt * 64 + tc] = T[g][tc];
    }
}

// ---------------- xW GEMM: M=32768 (b,s), N=4096, K=1024; out layout [s][b][4096] ----------------
__global__ void __launch_bounds__(256) gemm_xw(const unsigned short* __restrict__ x16,
                                               const unsigned short* __restrict__ w16t,
                                               void* __restrict__ xw, int mode) {
    const int nt = blockIdx.x & 63;
    const int mt = blockIdx.x >> 6;        // 0..511
    const int w = threadIdx.x >> 6;
    const int lane = threadIdx.x & 63;
    const int q = lane >> 4, l16 = lane & 15;

    const unsigned short* abase = x16 + (size_t)(mt * 64 + w * 16 + l16) * 1024 + q * 8;
    const unsigned short* bbase = w16t + (size_t)(nt * 64 + l16) * 1024 + q * 8;

    f32x4 acc[4] = {{0,0,0,0},{0,0,0,0},{0,0,0,0},{0,0,0,0}};
#pragma unroll 8
    for (int kk = 0; kk < 32; ++kk) {
        short8 a = *(const short8*)(abase + kk * 32);
#pragma unroll
        for (int j = 0; j < 4; ++j) {
            short8 b = *(const short8*)(bbase + (size_t)j * 16 * 1024 + kk * 32);
            acc[j] = __builtin_amdgcn_mfma_f32_16x16x32_bf16(a, b, acc[j], 0, 0, 0);
        }
    }
    const int m0 = mt * 64 + w * 16 + q * 4;
#pragma unroll
    for (int j = 0; j < 4; ++j)
#pragma unroll
        for (int r = 0; r < 4; ++r) {
            const int m = m0 + r;
            const int b = m >> 9, s = m & 511;
            const size_t o = ((size_t)s * 64 + b) * G4c + nt * 64 + j * 16 + l16;
            if (mode == 2) ((float*)xw)[o] = acc[j][r];
            else ((unsigned short*)xw)[o] = f2bf(acc[j][r]);
        }
}

// ---------------- per-block barrier: 64 WGs = 4 leaves x 16 -> root of 4 ----------------
__device__ __forceinline__ void blk_barrier(unsigned int* base, int cs, unsigned int gen) {
    __builtin_amdgcn_fence(__ATOMIC_RELEASE, "agent");
    __syncthreads();
    if (threadIdx.x == 0) {
        unsigned int a = __hip_atomic_fetch_add(&base[16 + 8 * (cs >> 4)], 1u, __ATOMIC_ACQ_REL, __HIP_MEMORY_SCOPE_AGENT);
        bool rel = false;
        if (a == 15u) {
            unsigned int r = __hip_atomic_fetch_add(&base[8], 1u, __ATOMIC_ACQ_REL, __HIP_MEMORY_SCOPE_AGENT);
            if (r == 3u) {
                __hip_atomic_store(&base[8], 0u, __ATOMIC_RELAXED, __HIP_MEMORY_SCOPE_AGENT);
#pragma unroll
                for (int g = 0; g < 4; ++g)
                    __hip_atomic_store(&base[16 + 8 * g], 0u, __ATOMIC_RELAXED, __HIP_MEMORY_SCOPE_AGENT);
                __hip_atomic_store(&base[0], gen, __ATOMIC_RELEASE, __HIP_MEMORY_SCOPE_AGENT);
                rel = true;
            }
        }
        if (!rel) {
            while (__hip_atomic_load(&base[0], __ATOMIC_RELAXED, __HIP_MEMORY_SCOPE_AGENT) < gen)
                __builtin_amdgcn_s_sleep(2);
        }
    }
    __syncthreads();
    __builtin_amdgcn_fence(__ATOMIC_ACQUIRE, "agent");
}

// ---------------- recurrence ----------------
__global__ void __launch_bounds__(256, 1) lstm_rec(
    const unsigned short* __restrict__ x16, const float* __restrict__ x,
    const unsigned short* __restrict__ w16t, const unsigned short* __restrict__ u16t,
    const float* __restrict__ bias, const void* __restrict__ xw,
    unsigned short* __restrict__ hbuf, unsigned int* __restrict__ bar,
    float* __restrict__ out, int xw_mode, int use_x16) {
    __shared__ short8 hsF[2048];   // 32 KB: A-frags of h, [kk][lane]
    __shared__ short8 xsF[2048];   // 32 KB: A-frags of x_t (mode 0 only)
    __shared__ float gbuf[4][16][17];

    const int tid = threadIdx.x;
    const int blk = blockIdx.x >> 6;      // batch block 0..3
    const int cs = blockIdx.x & 63;       // col slice 0..63
    const int col0 = cs * 16;
    const int wv = tid >> 6;
    const int lane = tid & 63;
    const int q = lane >> 4, l16 = lane & 15;
    const int bb = tid >> 4, cc = tid & 15;   // elementwise (batch, col)
    const int gcol = col0 + cc;
    unsigned int* bbar = bar + blk * 64;

    // bias registers
    const float bi = bias[gcol], bfv = bias[1024 + gcol], bg = bias[2048 + gcol], bo = bias[3072 + gcol];

    // U slice -> registers: 32 x short8 = 128 VGPRs
    short8 uf[32];
    {
        const unsigned short* ub = u16t + ((size_t)wv * 1024 + col0 + l16) * 1024 + q * 8;
#pragma unroll
        for (int kk = 0; kk < 32; ++kk) uf[kk] = *(const short8*)(ub + kk * 32);
    }
    // zero h frags (h_{-1} = 0)
    {
        const short8 z = {0, 0, 0, 0, 0, 0, 0, 0};
#pragma unroll
        for (int i = 0; i < 8; ++i) hsF[i * 256 + tid] = z;
    }
    // mode 0: stage x frags for t=0
    if (xw_mode == 0) {
#pragma unroll
        for (int i = 0; i < 8; ++i) {
            const int f = i * 256 + tid;
            const int kk = f >> 6, qq = (f >> 4) & 3, b2 = f & 15;
            if (use_x16) {
                const unsigned short* xs = x16 + ((size_t)(blk * 16 + b2) * Sc + 0) * Dc + kk * 32 + qq * 8;
                xsF[f] = *(const short8*)xs;
            } else {
                const float* xs = x + ((size_t)(blk * 16 + b2) * Sc + 0) * Dc + kk * 32 + qq * 8;
                float4 v0 = *(const float4*)xs, v1 = *(const float4*)(xs + 4);
                short8 s;
                s[0] = f2bfs(v0.x); s[1] = f2bfs(v0.y); s[2] = f2bfs(v0.z); s[3] = f2bfs(v0.w);
                s[4] = f2bfs(v1.x); s[5] = f2bfs(v1.y); s[6] = f2bfs(v1.z); s[7] = f2bfs(v1.w);
                xsF[f] = s;
            }
        }
    }
    // prefetch xW(t=0)
    float pxi = 0.f, pxf = 0.f, pxg = 0.f, pxo = 0.f;
    if (xw_mode == 1) {
        const unsigned short* p = (const unsigned short*)xw + ((size_t)0 * 64 + blk * 16 + bb) * G4c + gcol;
        pxi = bf2f(p[0]); pxf = bf2f(p[1024]); pxg = bf2f(p[2048]); pxo = bf2f(p[3072]);
    } else if (xw_mode == 2) {
        const float* p = (const float*)xw + ((size_t)0 * 64 + blk * 16 + bb) * G4c + gcol;
        pxi = p[0]; pxf = p[1024]; pxg = p[2048]; pxo = p[3072];
    }

    float c = 0.f;
    for (int t = 0; t < Sc; ++t) {
        __syncthreads();   // staging (or init) visible
        f32x4 a0 = {0, 0, 0, 0}, a1 = {0, 0, 0, 0};
#pragma unroll
        for (int kk = 0; kk < 32; kk += 2) {
            a0 = __builtin_amdgcn_mfma_f32_16x16x32_bf16(hsF[kk * 64 + lane], uf[kk], a0, 0, 0, 0);
            a1 = __builtin_amdgcn_mfma_f32_16x16x32_bf16(hsF[(kk + 1) * 64 + lane], uf[kk + 1], a1, 0, 0, 0);
        }
        if (xw_mode == 0) {
            const unsigned short* wb = w16t + ((size_t)wv * 1024 + col0 + l16) * 1024 + q * 8;
#pragma unroll
            for (int kk = 0; kk < 32; kk += 2) {
                short8 w0 = *(const short8*)(wb + kk * 32);
                a0 = __builtin_amdgcn_mfma_f32_16x16x32_bf16(xsF[kk * 64 + lane], w0, a0, 0, 0, 0);
                short8 w1 = *(const short8*)(wb + (kk + 1) * 32);
                a1 = __builtin_amdgcn_mfma_f32_16x16x32_bf16(xsF[(kk + 1) * 64 + lane], w1, a1, 0, 0, 0);
            }
        }
#pragma unroll
        for (int r = 0; r < 4; ++r) gbuf[wv][q * 4 + r][l16] = a0[r] + a1[r];
        __syncthreads();
        // elementwise: thread (bb, cc)
        float gi = gbuf[0][bb][cc] + pxi + bi;
        float gf = gbuf[1][bb][cc] + pxf + bfv;
        float gg = gbuf[2][bb][cc] + pxg + bg;
        float go = gbuf[3][bb][cc] + pxo + bo;
        gi = sigmoidf_(gi); gf = sigmoidf_(gf); gg = tanhf_(gg); go = sigmoidf_(go);
        c = gf * c + gi * gg;
        const float h = go * tanhf_(c);
        hbuf[(t & 1) * (Bc * Hc) + (blk * 16 + bb) * Hc + gcol] = f2bf(h);
        out[((size_t)(blk * 16 + bb) * Sc + t) * Hc + gcol] = h;
        if (t == Sc - 1) {
            out[(size_t)Bc * Sc * Hc + (size_t)(blk * 16 + bb) * Hc + gcol] = h;
            out[(size_t)Bc * Sc * Hc + (size_t)Bc * Hc + (size_t)(blk * 16 + bb) * Hc + gcol] = c;
        }
        if (t < Sc - 1) {
            // prefetch xW(t+1) before the barrier (latency hidden behind spin)
            if (xw_mode == 1) {
                const unsigned short* p = (const unsigned short*)xw + ((size_t)(t + 1) * 64 + blk * 16 + bb) * G4c + gcol;
                pxi = bf2f(p[0]); pxf = bf2f(p[1024]); pxg = bf2f(p[2048]); pxo = bf2f(p[3072]);
            } else if (xw_mode == 2) {
                const float* p = (const float*)xw + ((size_t)(t + 1) * 64 + blk * 16 + bb) * G4c + gcol;
                pxi = p[0]; pxf = p[1024]; pxg = p[2048]; pxo = p[3072];
            }
            blk_barrier(bbar, cs, (unsigned int)(t + 1));
            // stage h_t frags
            const unsigned short* hsrc = hbuf + (t & 1) * (Bc * Hc) + blk * 16 * Hc;
#pragma unroll
            for (int i = 0; i < 8; ++i) {
                const int f = i * 256 + tid;
                const int kk = f >> 6, qq = (f >> 4) & 3, b2 = f & 15;
                hsF[f] = *(const short8*)(hsrc + (size_t)b2 * Hc + kk * 32 + qq * 8);
            }
            // stage x_{t+1} frags (mode 0)
            if (xw_mode == 0) {
#pragma unroll
                for (int i = 0; i < 8; ++i) {
                    const int f = i * 256 + tid;
                    const int kk = f >> 6, qq = (f >> 4) & 3, b2 = f & 15;
                    if (use_x16) {
                        const unsigned short* xs = x16 + ((size_t)(blk * 16 + b2) * Sc + (t + 1)) * Dc + kk * 32 + qq * 8;
                        xsF[f] = *(const short8*)xs;
                    } else {
                        const float* xs = x + ((size_t)(blk * 16 + b2) * Sc + (t + 1)) * Dc + kk * 32 + qq * 8;
                        float4 v0 = *(const float4*)xs, v1 = *(const float4*)(xs + 4);
                        short8 s;
                        s[0] = f2bfs(v0.x); s[1] = f2bfs(v0.y); s[2] = f2bfs(v0.z); s[3] = f2bfs(v0.w);
                        s[4] = f2bfs(v1.x); s[5] = f2bfs(v1.y); s[6] = f2bfs(v1.z); s[7] = f2bfs(v1.w);
                        xsF[f] = s;
                    }
                }
            }
        }
    }
}

extern "C" void kernel_launch(void* const* d_in, const int* in_sizes, int n_in,
                              void* d_out, int out_size, void* d_ws, size_t ws_size,
                              hipStream_t stream) {
    const float* x = (const float*)d_in[0];
    const float* W = (const float*)d_in[1];
    const float* U = (const float*)d_in[2];
    const float* bias = (const float*)d_in[3];
    float* out = (float*)d_out;

    char* wsb = (char*)d_ws;
    // layout: bar(4K) | hbuf(256K) | U16T(8M) | W16T(8M) | x16(64M) | xW
    unsigned int* bar = (unsigned int*)wsb;
    unsigned short* hbuf = (unsigned short*)(wsb + 4096);
    unsigned short* u16t = (unsigned short*)(wsb + 266240);
    unsigned short* w16t = (unsigned short*)(wsb + 266240 + 8388608);
    unsigned short* x16 = (unsigned short*)(wsb + 17043456);
    void* xw = (void*)(wsb + 84152320);

    const size_t base_no_x16 = 17043456ull;
    const size_t base = 84152320ull;
    const size_t need1 = base + 268435456ull;   // xW bf16
    const size_t need2 = base + 536870912ull;   // xW fp32

    int xw_mode, use_x16;
    if (ws_size >= need2)      { xw_mode = 2; use_x16 = 1; }
    else if (ws_size >= need1) { xw_mode = 1; use_x16 = 1; }
    else if (ws_size >= base)  { xw_mode = 0; use_x16 = 1; }
    else                       { xw_mode = 0; use_x16 = 0; (void)base_no_x16; }

    const int n4 = (Bc * Sc * Dc) / 4;
    hipLaunchKernelGGL(prep_misc, dim3(2048), dim3(256), 0, stream, x, x16, bar, n4, use_x16);
    hipLaunchKernelGGL(transpose_bf16, dim3(1024), dim3(256), 0, stream, U, u16t);
    hipLaunchKernelGGL(transpose_bf16, dim3(1024), dim3(256), 0, stream, W, w16t);
    if (xw_mode >= 1)
        hipLaunchKernelGGL(gemm_xw, dim3(32768), dim3(256), 0, stream, x16, w16t, xw, xw_mode);
    hipLaunchKernelGGL(lstm_rec, dim3(256), dim3(256), 0, stream,
                       x16, x, w16t, u16t, bias, xw, hbuf, bar, out, xw_mode, use_x16);
}